// Round 1
// baseline (51.142 us; speedup 1.0000x reference)
//
#include <hip/hip_runtime.h>

// Scatter-add inverted to gather, scan-free:
//   memset(counts) -> fill (padded buckets, int atomics) -> gather (one wave
//   per output row, writes every row exactly once, no fp atomics, no d_out
//   memset).
// MAXD=12 padded slots per output row. 32768 sources over 65536 rows is
// Poisson(0.5): P(count>12 anywhere) ~ 1e-5. Overflow is still CORRECT via a
// rescan-of-idx fallback (slow path, effectively never taken).
//
// This revision vs. previous (40.8 us):
//  - gather lane layout: lane owns cols [lane*4,+4) and [C/2+lane*4,+4) so
//    every global load/store instruction is one fully-contiguous 1024 B
//    wave-segment (was 16 B at 32 B stride = half-filled 64 B segments,
//    2x L2 requests on 192 MiB of streaming traffic).
//  - nontemporal loads on input rows (read-once) and nontemporal stores on
//    output (write-once, never re-read): no L2 allocate for pure streams.

#define MAXD 12

typedef float f32x4 __attribute__((ext_vector_type(4)));

__global__ void fill_kernel(const int* __restrict__ idx, int* __restrict__ counts,
                            int* __restrict__ row_ids, int n) {
    int i = blockIdx.x * blockDim.x + threadIdx.x;
    if (i < n) {
        int d = idx[i];
        int pos = atomicAdd(&counts[d], 1);
        if (pos < MAXD) row_ids[d * MAXD + pos] = i;
    }
}

// One wave per output row; lane owns 4 floats in each half of the row (C=512).
__global__ void __launch_bounds__(256) gather_kernel(
        const float* __restrict__ in,
        const int* __restrict__ counts,
        const int* __restrict__ row_ids,
        const int* __restrict__ idx,
        float* __restrict__ out, int C, int n_rows) {
    int wave = blockIdx.x * (blockDim.x >> 6) + (threadIdx.x >> 6);
    int lane = threadIdx.x & 63;

    int cnt = counts[wave];
    // Load up to MAXD source ids with one coalesced vector load, then
    // broadcast via shfl (avoids cnt dependent scalar loads).
    int myid = (lane < MAXD && lane < cnt) ? row_ids[wave * MAXD + lane] : -1;

    f32x4 a0 = 0.f;
    f32x4 a1 = 0.f;

    long col0 = (long)lane * 4;          // bytes [0,1024) of the row
    long col1 = (long)(C >> 1) + lane * 4;  // bytes [1024,2048) of the row

    int m = (cnt < MAXD) ? cnt : MAXD;
    for (int j = 0; j < m; ++j) {
        int src = __shfl(myid, j);              // wave-uniform
        const f32x4* p0 = reinterpret_cast<const f32x4*>(in + (long)src * C + col0);
        const f32x4* p1 = reinterpret_cast<const f32x4*>(in + (long)src * C + col1);
        f32x4 v0 = __builtin_nontemporal_load(p0);
        f32x4 v1 = __builtin_nontemporal_load(p1);
        a0 += v0;
        a1 += v1;
    }

    if (cnt > MAXD) {
        // Overflow fallback (probability ~1e-5 for this distribution, but
        // keeps the kernel correct unconditionally): rescan idx for sources
        // of this row that were not captured in the padded bucket.
        for (int r = 0; r < n_rows; ++r) {
            if (__builtin_expect(idx[r] == wave, 0)) {
                bool captured = __any((lane < MAXD) && (myid == r));
                if (!captured) {
                    const f32x4* p0 = reinterpret_cast<const f32x4*>(in + (long)r * C + col0);
                    const f32x4* p1 = reinterpret_cast<const f32x4*>(in + (long)r * C + col1);
                    a0 += *p0;
                    a1 += *p1;
                }
            }
        }
    }

    __builtin_nontemporal_store(a0, reinterpret_cast<f32x4*>(out + (long)wave * C + col0));
    __builtin_nontemporal_store(a1, reinterpret_cast<f32x4*>(out + (long)wave * C + col1));
}

extern "C" void kernel_launch(void* const* d_in, const int* in_sizes, int n_in,
                              void* d_out, int out_size, void* d_ws, size_t ws_size,
                              hipStream_t stream) {
    const float* in  = (const float*)d_in[0];
    const int*   idx = (const int*)d_in[1];
    float*       out = (float*)d_out;

    int n_rows = in_sizes[1];             // 32768 sources
    int C      = in_sizes[0] / n_rows;    // 512
    int R      = out_size / C;            // 65536 output rows (B*L)

    int* counts  = (int*)d_ws;            // R ints
    int* row_ids = counts + R;            // R*MAXD ints (~3 MiB)

    hipMemsetAsync(counts, 0, (size_t)R * sizeof(int), stream);

    int block = 256;
    fill_kernel<<<(n_rows + block - 1) / block, block, 0, stream>>>(idx, counts, row_ids, n_rows);

    int waves_per_block = block / 64;     // one wave per output row
    int grid = (R + waves_per_block - 1) / waves_per_block;
    gather_kernel<<<grid, block, 0, stream>>>(in, counts, row_ids, idx, out, C, n_rows);
}

// Round 2
// 41.258 us; speedup vs baseline: 1.2396x; 1.2396x over previous
//
#include <hip/hip_runtime.h>

// Scatter-add inverted to gather, scan-free:
//   memset(counts) -> fill (padded buckets, int atomics) -> gather (one wave
//   per output row, writes every row exactly once, no fp atomics, no d_out
//   memset).
// MAXD=12 padded slots per output row. 32768 sources over 65536 rows is
// Poisson(0.5): P(count>12 anywhere) ~ 1e-5. Overflow is still CORRECT via a
// rescan-of-idx fallback (slow path, effectively never taken).
//
// Revision history:
//  - r0 (40.8 us): lane owns 8 consecutive floats; plain loads/stores.
//  - r1 (51.1 us, REGRESSED): contiguous-segment lane layout + nontemporal
//    hints. Post-mortem theory: NT hints defeated L2 write-combining on the
//    128 MiB output stream (fillBuffer hits 6.9 TB/s with normal stores).
//  - r2 (this): keep contiguous layout, DROP all NT hints.

#define MAXD 12

typedef float f32x4 __attribute__((ext_vector_type(4)));

__global__ void fill_kernel(const int* __restrict__ idx, int* __restrict__ counts,
                            int* __restrict__ row_ids, int n) {
    int i = blockIdx.x * blockDim.x + threadIdx.x;
    if (i < n) {
        int d = idx[i];
        int pos = atomicAdd(&counts[d], 1);
        if (pos < MAXD) row_ids[d * MAXD + pos] = i;
    }
}

// One wave per output row; lane owns 4 floats in each half of the row (C=512).
__global__ void __launch_bounds__(256) gather_kernel(
        const float* __restrict__ in,
        const int* __restrict__ counts,
        const int* __restrict__ row_ids,
        const int* __restrict__ idx,
        float* __restrict__ out, int C, int n_rows) {
    int wave = blockIdx.x * (blockDim.x >> 6) + (threadIdx.x >> 6);
    int lane = threadIdx.x & 63;

    int cnt = counts[wave];
    // Load up to MAXD source ids with one coalesced vector load, then
    // broadcast via shfl (avoids cnt dependent scalar loads).
    int myid = (lane < MAXD && lane < cnt) ? row_ids[wave * MAXD + lane] : -1;

    f32x4 a0 = 0.f;
    f32x4 a1 = 0.f;

    long col0 = (long)lane * 4;             // bytes [0,1024) of the row
    long col1 = (long)(C >> 1) + lane * 4;  // bytes [1024,2048) of the row

    int m = (cnt < MAXD) ? cnt : MAXD;
    for (int j = 0; j < m; ++j) {
        int src = __shfl(myid, j);              // wave-uniform
        const f32x4* p0 = reinterpret_cast<const f32x4*>(in + (long)src * C + col0);
        const f32x4* p1 = reinterpret_cast<const f32x4*>(in + (long)src * C + col1);
        f32x4 v0 = *p0;
        f32x4 v1 = *p1;
        a0 += v0;
        a1 += v1;
    }

    if (cnt > MAXD) {
        // Overflow fallback (probability ~1e-5 for this distribution, but
        // keeps the kernel correct unconditionally): rescan idx for sources
        // of this row that were not captured in the padded bucket.
        for (int r = 0; r < n_rows; ++r) {
            if (__builtin_expect(idx[r] == wave, 0)) {
                bool captured = __any((lane < MAXD) && (myid == r));
                if (!captured) {
                    const f32x4* p0 = reinterpret_cast<const f32x4*>(in + (long)r * C + col0);
                    const f32x4* p1 = reinterpret_cast<const f32x4*>(in + (long)r * C + col1);
                    a0 += *p0;
                    a1 += *p1;
                }
            }
        }
    }

    *reinterpret_cast<f32x4*>(out + (long)wave * C + col0) = a0;
    *reinterpret_cast<f32x4*>(out + (long)wave * C + col1) = a1;
}

extern "C" void kernel_launch(void* const* d_in, const int* in_sizes, int n_in,
                              void* d_out, int out_size, void* d_ws, size_t ws_size,
                              hipStream_t stream) {
    const float* in  = (const float*)d_in[0];
    const int*   idx = (const int*)d_in[1];
    float*       out = (float*)d_out;

    int n_rows = in_sizes[1];             // 32768 sources
    int C      = in_sizes[0] / n_rows;    // 512
    int R      = out_size / C;            // 65536 output rows (B*L)

    int* counts  = (int*)d_ws;            // R ints
    int* row_ids = counts + R;            // R*MAXD ints (~3 MiB)

    hipMemsetAsync(counts, 0, (size_t)R * sizeof(int), stream);

    int block = 256;
    fill_kernel<<<(n_rows + block - 1) / block, block, 0, stream>>>(idx, counts, row_ids, n_rows);

    int waves_per_block = block / 64;     // one wave per output row
    int grid = (R + waves_per_block - 1) / waves_per_block;
    gather_kernel<<<grid, block, 0, stream>>>(in, counts, row_ids, idx, out, C, n_rows);
}